// Round 5
// baseline (1121.192 us; speedup 1.0000x reference)
//
#include <hip/hip_runtime.h>

typedef __attribute__((ext_vector_type(8))) short short8;
typedef __attribute__((ext_vector_type(4))) float f32x4;

__device__ __forceinline__ ushort f2bf(float x) {
  unsigned u = __builtin_bit_cast(unsigned, x);
  u = (u + 0x7fffu + ((u >> 16) & 1u)) >> 16;
  return (ushort)u;
}
__device__ __forceinline__ float bf2f(ushort x) {
  return __builtin_bit_cast(float, ((unsigned)x) << 16);
}

// global -> LDS direct DMA (size literal; HW-verified 4 and 16 only)
#define AS1CP(p) ((const __attribute__((address_space(1))) unsigned int*)(p))
#define AS3CP(p) ((__attribute__((address_space(3))) unsigned int*)(p))
#define GLDS(g, l, SZ) __builtin_amdgcn_global_load_lds(AS1CP(g), AS3CP(l), SZ, 0, 0)

// ---------------- input fp32 -> bf16 ----------------
__global__ __launch_bounds__(256) void k_cvt(const float* __restrict__ in,
                                             ushort* __restrict__ out, int n4) {
  int i = blockIdx.x * 256 + threadIdx.x;
  if (i >= n4) return;
  float4 v = reinterpret_cast<const float4*>(in)[i];
  ushort4 o;
  o.x = f2bf(v.x); o.y = f2bf(v.y); o.z = f2bf(v.z); o.w = f2bf(v.w);
  reinterpret_cast<ushort4*>(out)[i] = o;
}

// ------------- transpose fp32 [K][N] -> bf16 [N][K] -------------
__global__ __launch_bounds__(256) void k_transpose(const float* __restrict__ W,
                                                   ushort* __restrict__ Wt,
                                                   int N, int K) {
  __shared__ float tile[32][33];
  int bx = blockIdx.x * 32;  // N dim
  int by = blockIdx.y * 32;  // K dim
  int tx = threadIdx.x, ty = threadIdx.y;  // 32 x 8
#pragma unroll
  for (int i = 0; i < 32; i += 8)
    tile[ty + i][tx] = W[(size_t)(by + ty + i) * N + bx + tx];
  __syncthreads();
#pragma unroll
  for (int i = 0; i < 32; i += 8)
    Wt[(size_t)(bx + ty + i) * K + by + tx] = f2bf(tile[tx][ty + i]);
}

// ------------- GEMM (m97-style): C[M][N] = A[M][K] bf16 * Bt[N][K] bf16 -----
// 128x128 tile, BK=32, 256 threads (4 waves 2x2 of 64x64), staging via
// global_load_lds width=16 (4 per thread per K-step), 2 barriers per K-step.
// BF16OUT: 0 -> fp32 C, 1 -> bf16 C.
template <int BF16OUT>
__global__ __launch_bounds__(256) void k_gemm(const ushort* __restrict__ A,
                                              const ushort* __restrict__ Bt,
                                              void* __restrict__ Cv,
                                              int K, int N) {
  __shared__ __align__(16) ushort lsA[128 * 32];
  __shared__ __align__(16) ushort lsB[128 * 32];
  const int tid = threadIdx.x;
  const int bm = blockIdx.x, bn = blockIdx.y;
  const int w = tid >> 6, l = tid & 63;
  const int wm = (w >> 1) * 64, wn = (w & 1) * 64;
  const int lr = l & 15, lg = l >> 4;
  f32x4 acc[4][4] = {};
  // staging: thread tid covers row = tid>>2 (and +64), 8 elems at col (tid&3)*8
  const int srow = tid >> 2;
  const int scol = (tid & 3) * 8;
  const ushort* Ag = A + (size_t)(bm * 128 + srow) * K + scol;
  const ushort* Bg = Bt + (size_t)(bn * 128 + srow) * K + scol;
  // wave-uniform LDS bases; HW writes lane*16 B from each base
  ushort* lA0 = lsA + w * 512;         // rows 0..63  : bytes w*1024 + lane*16
  ushort* lA1 = lsA + 2048 + w * 512;  // rows 64..127
  ushort* lB0 = lsB + w * 512;
  ushort* lB1 = lsB + 2048 + w * 512;

  for (int kt = 0; kt < K; kt += 32) {
    GLDS(Ag + kt, lA0, 16);
    GLDS(Ag + (size_t)64 * K + kt, lA1, 16);
    GLDS(Bg + kt, lB0, 16);
    GLDS(Bg + (size_t)64 * K + kt, lB1, 16);
    __syncthreads();  // compiler drains vmcnt before barrier -> tiles landed
    short8 af[4], bfr[4];
#pragma unroll
    for (int i = 0; i < 4; ++i)
      af[i] = *(const short8*)&lsA[(wm + i * 16 + lr) * 32 + lg * 8];
#pragma unroll
    for (int j = 0; j < 4; ++j)
      bfr[j] = *(const short8*)&lsB[(wn + j * 16 + lr) * 32 + lg * 8];
#pragma unroll
    for (int i = 0; i < 4; ++i)
#pragma unroll
      for (int j = 0; j < 4; ++j)
        acc[i][j] = __builtin_amdgcn_mfma_f32_16x16x32_bf16(af[i], bfr[j], acc[i][j], 0, 0, 0);
    __syncthreads();  // protect LDS before next stage overwrites
  }
  const size_t cbase = (size_t)(bm * 128 + wm + lg * 4) * N + bn * 128 + wn + lr;
  if (BF16OUT) {
    ushort* Cb = (ushort*)Cv + cbase;
#pragma unroll
    for (int i = 0; i < 4; ++i)
#pragma unroll
      for (int j = 0; j < 4; ++j)
#pragma unroll
        for (int r = 0; r < 4; ++r)
          Cb[(size_t)(i * 16 + r) * N + j * 16] = f2bf(acc[i][j][r]);
  } else {
    float* Cb = (float*)Cv + cbase;
#pragma unroll
    for (int i = 0; i < 4; ++i)
#pragma unroll
      for (int j = 0; j < 4; ++j)
#pragma unroll
        for (int r = 0; r < 4; ++r)
          Cb[(size_t)(i * 16 + r) * N + j * 16] = acc[i][j][r];
  }
}

// ------------- SRU recurrence: global_load_lds ring pipeline -------------
template <int KK>
__device__ __forceinline__ void issue_tile(const float* Ub, const ushort* Xb,
                                           float* ldsu, ushort* ldsx, int i,
                                           int t0, int tstep, int lane, int c0,
                                           int rs) {
  const int base = i * 16;
#pragma unroll
  for (int t = 0; t < 16; ++t) {
    int tt = t0 + tstep * (base + t);
    GLDS(Ub + (size_t)tt * rs, ldsu + t * 256, 16);
  }
  if (KK == 3) {
#pragma unroll
    for (int tp = 0; tp < 8; ++tp) {
      int tt = t0 + tstep * (base + tp * 2 + (lane >> 5));
      GLDS(Xb + (size_t)tt * 1024 + c0 + ((lane & 31) << 1), ldsx + tp * 128, 4);
    }
  }
}

template <int KK>
__device__ __forceinline__ void tile_wait(int i) {
  if (KK == 3) {  // 24 loads/tile; newer loads: steady 72 (cap 63), 48, 24, 0
    if (i <= 28)
      asm volatile("s_waitcnt vmcnt(63)" ::: "memory");
    else if (i == 29)
      asm volatile("s_waitcnt vmcnt(48)" ::: "memory");
    else if (i == 30)
      asm volatile("s_waitcnt vmcnt(24)" ::: "memory");
    else
      asm volatile("s_waitcnt vmcnt(0)" ::: "memory");
  } else {        // 16 loads/tile; newer loads: steady 48, 32, 16, 0
    if (i <= 28)
      asm volatile("s_waitcnt vmcnt(48)" ::: "memory");
    else if (i == 29)
      asm volatile("s_waitcnt vmcnt(32)" ::: "memory");
    else if (i == 30)
      asm volatile("s_waitcnt vmcnt(16)" ::: "memory");
    else
      asm volatile("s_waitcnt vmcnt(0)" ::: "memory");
  }
}

template <int KK>
__device__ __forceinline__ void compute_tile(const float* tu, const ushort* tx,
                                             int i, int t0, int tstep, int lane,
                                             float vf, float vr, float bfv,
                                             float brv, float& c, ushort* Hb) {
#pragma unroll
  for (int s = 0; s < 16; ++s) {
    float4 p = *(const float4*)(tu + s * 256 + lane * 4);
    float u0 = p.x, u1 = p.y, u2 = p.z;
    float u3 = (KK == 4) ? p.w : bf2f(tx[s * 64 + lane]);
    float f = 1.f / (1.f + __expf(-(u1 + vf * c + bfv)));
    c = f * c + (1.f - f) * u0;
    float r = 1.f / (1.f + __expf(-(u2 + vr * c + brv)));
    float hh = r * c + (1.f - r) * u3;
    Hb[(size_t)(t0 + tstep * (i * 16 + s)) * 1024] = f2bf(hh);
  }
}

template <int KK>
__global__ __launch_bounds__(64) void sru_rec2(const float* __restrict__ U,
                                               const ushort* __restrict__ Xres,
                                               const float* __restrict__ v,
                                               const float* __restrict__ bb,
                                               ushort* __restrict__ H) {
  const int NT = 32;
  __shared__ __align__(16) float lsU[4][16 * 256];   // 64 KB
  __shared__ __align__(16) ushort lsX[4][16 * 64];   // 8 KB (KK3 only)
  const int lane = threadIdx.x;
  const int blk = blockIdx.x;                            // 0..255
  const int b = blk >> 4, rem = blk & 15, dir = rem >> 3, c0 = (rem & 7) << 6;
  const int h = c0 + lane;
  const float vf = v[dir * 512 + h], vr = v[1024 + dir * 512 + h];
  const float bfv = bb[dir * 512 + h], brv = bb[1024 + dir * 512 + h];
  const int rs = 1024 * KK;
  const int tstep = dir ? -1 : 1;
  const int t0 = dir ? 511 : 0;
  const float* Ub = U + (size_t)b * 512 * rs + dir * 512 * KK + (size_t)h * KK;
  const ushort* Xb = Xres + (size_t)b * 512 * 1024 + dir * 512;
  ushort* Hb = H + (size_t)b * 512 * 1024 + dir * 512 + h;

  issue_tile<KK>(Ub, Xb, &lsU[0][0], &lsX[0][0], 0, t0, tstep, lane, c0, rs);
  issue_tile<KK>(Ub, Xb, &lsU[1][0], &lsX[1][0], 1, t0, tstep, lane, c0, rs);
  issue_tile<KK>(Ub, Xb, &lsU[2][0], &lsX[2][0], 2, t0, tstep, lane, c0, rs);

  float c = 0.f;
#pragma unroll 1
  for (int ii = 0; ii < NT / 4; ++ii) {
#define TILE_J(J)                                                              \
    {                                                                          \
      const int i = ii * 4 + (J);                                              \
      if (i + 3 < NT)                                                          \
        issue_tile<KK>(Ub, Xb, &lsU[((J) + 3) & 3][0], &lsX[((J) + 3) & 3][0], \
                       i + 3, t0, tstep, lane, c0, rs);                        \
      tile_wait<KK>(i);                                                        \
      compute_tile<KK>(&lsU[(J) & 3][0], &lsX[(J) & 3][0], i, t0, tstep, lane, \
                       vf, vr, bfv, brv, c, Hb);                               \
    }
    TILE_J(0) TILE_J(1) TILE_J(2) TILE_J(3)
#undef TILE_J
  }
}

// ------------- head helpers -------------
// Combined fc2 weight, [N=128][K=1024] bf16: cols(n) 0..20 <- w2l (k<512),
// 21..22 <- w2m (k>=512), 23..24 <- w2k (k>=512), else 0.
__global__ __launch_bounds__(256) void k_buildW2(const float* __restrict__ w2l,
                                                 const float* __restrict__ w2m,
                                                 const float* __restrict__ w2k,
                                                 ushort* __restrict__ Wt2) {
  int i = blockIdx.x * 256 + threadIdx.x;  // over 128*1024
  if (i >= 128 * 1024) return;
  int n = i >> 10, k = i & 1023;
  float vv = 0.f;
  if (n < 21 && k < 512) vv = w2l[k * 21 + n];
  else if (n >= 21 && n < 23 && k >= 512) vv = w2m[(k - 512) * 2 + (n - 21)];
  else if (n >= 23 && n < 25 && k >= 512) vv = w2k[(k - 512) * 2 + (n - 23)];
  Wt2[i] = f2bf(vv);
}

// Adjusted output bias: b2adj[o] = b2[o] + sum_k b1[k] * w2[k][o]
__global__ __launch_bounds__(64) void k_bias25(const float* __restrict__ b1l,
                                               const float* __restrict__ b1a,
                                               const float* __restrict__ w2l,
                                               const float* __restrict__ b2l,
                                               const float* __restrict__ w2m,
                                               const float* __restrict__ b2m,
                                               const float* __restrict__ w2k,
                                               const float* __restrict__ b2k,
                                               float* __restrict__ b2adj) {
  int o = threadIdx.x;
  if (o >= 25) return;
  float s;
  if (o < 21) {
    s = b2l[o];
    for (int k = 0; k < 512; ++k) s += b1l[k] * w2l[k * 21 + o];
  } else if (o < 23) {
    s = b2m[o - 21];
    for (int k = 0; k < 512; ++k) s += b1a[k] * w2m[k * 2 + (o - 21)];
  } else {
    s = b2k[o - 23];
    for (int k = 0; k < 512; ++k) s += b1a[k] * w2k[k * 2 + (o - 23)];
  }
  b2adj[o] = s;
}

// Final activations: one wave per row; T[row][0..24] fp32 (+b2adj applied).
__global__ __launch_bounds__(64) void k_act(const float* __restrict__ T,
                                            const float* __restrict__ b2adj,
                                            float* __restrict__ out) {
  const int row = blockIdx.x;
  const int lane = threadIdx.x;
  float myv = 0.f;
  if (lane < 25) myv = T[(size_t)row * 128 + lane] + b2adj[lane];
  float x = (lane < 21) ? myv : -1e30f;
#pragma unroll
  for (int off = 32; off; off >>= 1) x = fmaxf(x, __shfl_xor(x, off));
  float e = (lane < 21) ? expf(myv - x) : 0.f;
#pragma unroll
  for (int off = 32; off; off >>= 1) e += __shfl_xor(e, off);
  float lse = x + logf(e);
  if (lane < 21) {
    out[(size_t)row * 21 + lane] = myv - lse;
  } else if (lane < 23) {
    out[172032 + row * 2 + (lane - 21)] = tanhf(myv) * 3.14159265358979323846f;
  } else if (lane < 25) {
    float sp = (myv > 20.f) ? myv : log1pf(expf(myv));
    out[188416 + row * 2 + (lane - 23)] = 5.f + sp;
  }
}

extern "C" void kernel_launch(void* const* d_in, const int* in_sizes, int n_in,
                              void* d_out, int out_size, void* d_ws, size_t ws_size,
                              hipStream_t stream) {
  (void)in_sizes; (void)n_in; (void)out_size; (void)ws_size;
  const float* input = (const float*)d_in[0];
  const float* sw[6]; const float* sv[6]; const float* sb[6];
  for (int l = 0; l < 6; ++l) {
    sw[l] = (const float*)d_in[2 + 3 * l];
    sv[l] = (const float*)d_in[3 + 3 * l];
    sb[l] = (const float*)d_in[4 + 3 * l];
  }
  const float* fc1lw = (const float*)d_in[20];
  const float* fc1lb = (const float*)d_in[21];
  const float* fc2lw = (const float*)d_in[22];
  const float* fc2lb = (const float*)d_in[23];
  const float* fc1aw = (const float*)d_in[24];
  const float* fc1ab = (const float*)d_in[25];
  const float* fc2mw = (const float*)d_in[26];
  const float* fc2mb = (const float*)d_in[27];
  const float* fc2kw = (const float*)d_in[28];
  const float* fc2kb = (const float*)d_in[29];

  char* ws = (char*)d_ws;
  float* U = (float*)ws;                                   // 128 MiB
  ushort* Hcat2 = (ushort*)ws;                             // 16 MiB (reuses U after layers)
  float* T = (float*)(ws + 67108864);                      // 4 MiB (inside old U region)
  ushort* H0 = (ushort*)(ws + 134217728);                  // 16 MiB
  ushort* H1 = (ushort*)(ws + 150994944);                  // 16 MiB
  ushort* X0 = (ushort*)(ws + 167772160);                  // 8 MiB
  const size_t wbase = 176160768;
  ushort* Wtl[6];
  Wtl[0] = (ushort*)(ws + wbase);                          // 4 MiB
  for (int l = 1; l < 6; ++l)
    Wtl[l] = (ushort*)(ws + wbase + 4194304 + (size_t)(l - 1) * 6291456);  // 6 MiB each
  ushort* Wfc = (ushort*)(ws + wbase + 4194304 + 5ull * 6291456);          // 2 MiB
  ushort* Wt2 = (ushort*)(ws + wbase + 37748736);          // 256 KiB
  float* b2adj = (float*)(ws + wbase + 38010880);          // 100 B

  // 1. input -> bf16; head weight prep
  k_cvt<<<4096, 256, 0, stream>>>(input, X0, 8192 * 512 / 4);
  k_buildW2<<<512, 256, 0, stream>>>(fc2lw, fc2mw, fc2kw, Wt2);
  k_bias25<<<1, 64, 0, stream>>>(fc1lb, fc1ab, fc2lw, fc2lb, fc2mw, fc2mb,
                                 fc2kw, fc2kb, b2adj);

  // 2. weight transposes -> bf16 [N][K]
  k_transpose<<<dim3(4096 / 32, 512 / 32), dim3(32, 8), 0, stream>>>(sw[0], Wtl[0], 4096, 512);
  for (int l = 1; l < 6; ++l)
    k_transpose<<<dim3(3072 / 32, 1024 / 32), dim3(32, 8), 0, stream>>>(sw[l], Wtl[l], 3072, 1024);
  k_transpose<<<dim3(512 / 32, 1024 / 32), dim3(32, 8), 0, stream>>>(fc1lw, Wfc, 512, 1024);
  k_transpose<<<dim3(512 / 32, 1024 / 32), dim3(32, 8), 0, stream>>>(fc1aw, Wfc + (size_t)512 * 1024, 512, 1024);

  // 3. SRU layers
  for (int l = 0; l < 6; ++l) {
    const ushort* Ain = (l == 0) ? X0 : ((l & 1) ? H0 : H1);
    ushort* Hout = (l & 1) ? H1 : H0;
    int K = (l == 0) ? 512 : 1024;
    int N = (l == 0) ? 4096 : 3072;
    k_gemm<0><<<dim3(64, N / 128), 256, 0, stream>>>(Ain, Wtl[l], U, K, N);
    if (l == 0)
      sru_rec2<4><<<256, 64, 0, stream>>>(U, X0 /*unused*/, sv[l], sb[l], Hout);
    else
      sru_rec2<3><<<256, 64, 0, stream>>>(U, Ain, sv[l], sb[l], Hout);
  }

  // 4. head fc1 (logits|angles fused), bf16 out: [8192,1024] = H1 x Wfc
  k_gemm<1><<<dim3(64, 8), 256, 0, stream>>>(H1, Wfc, Hcat2, 1024, 1024);

  // 5. head fc2: [8192,128] = Hcat2[8192,1024] x Wt2[128,1024]
  k_gemm<0><<<dim3(64, 1), 256, 0, stream>>>(Hcat2, Wt2, T, 1024, 128);

  // 6. activations -> out
  k_act<<<8192, 64, 0, stream>>>(T, b2adj, (float*)d_out);
}

// Round 6
// 1008.960 us; speedup vs baseline: 1.1112x; 1.1112x over previous
//
#include <hip/hip_runtime.h>

typedef __attribute__((ext_vector_type(8))) short short8;
typedef __attribute__((ext_vector_type(4))) float f32x4;

__device__ __forceinline__ ushort f2bf(float x) {
  unsigned u = __builtin_bit_cast(unsigned, x);
  u = (u + 0x7fffu + ((u >> 16) & 1u)) >> 16;
  return (ushort)u;
}
__device__ __forceinline__ float bf2f(ushort x) {
  return __builtin_bit_cast(float, ((unsigned)x) << 16);
}

// global -> LDS direct DMA (size literal; HW-verified 4 and 16 only)
#define AS1CP(p) ((const __attribute__((address_space(1))) unsigned int*)(p))
#define AS3CP(p) ((__attribute__((address_space(3))) unsigned int*)(p))
#define GLDS(g, l, SZ) __builtin_amdgcn_global_load_lds(AS1CP(g), AS3CP(l), SZ, 0, 0)

// ---------------- input fp32 -> bf16 ----------------
__global__ __launch_bounds__(256) void k_cvt(const float* __restrict__ in,
                                             ushort* __restrict__ out, int n4) {
  int i = blockIdx.x * 256 + threadIdx.x;
  if (i >= n4) return;
  float4 v = reinterpret_cast<const float4*>(in)[i];
  ushort4 o;
  o.x = f2bf(v.x); o.y = f2bf(v.y); o.z = f2bf(v.z); o.w = f2bf(v.w);
  reinterpret_cast<ushort4*>(out)[i] = o;
}

// ------------- transpose fp32 [K][N] -> bf16 [N][K] -------------
__global__ __launch_bounds__(256) void k_transpose(const float* __restrict__ W,
                                                   ushort* __restrict__ Wt,
                                                   int N, int K) {
  __shared__ float tile[32][33];
  int bx = blockIdx.x * 32;  // N dim
  int by = blockIdx.y * 32;  // K dim
  int tx = threadIdx.x, ty = threadIdx.y;  // 32 x 8
#pragma unroll
  for (int i = 0; i < 32; i += 8)
    tile[ty + i][tx] = W[(size_t)(by + ty + i) * N + bx + tx];
  __syncthreads();
#pragma unroll
  for (int i = 0; i < 32; i += 8)
    Wt[(size_t)(bx + ty + i) * K + by + tx] = f2bf(tile[tx][ty + i]);
}

// ------------- GEMM: C[M][N] = A[M][K] bf16 * Bt[N][K] bf16 -------------
// 128x128 tile, BK=32, 256 threads (4 waves 2x2 of 64x64). Double-buffered
// global_load_lds staging: issue next tile at loop top, counted vmcnt(4),
// raw s_barrier pair per K-step (loads stay in flight across MFMA).
template <int BF16OUT>
__global__ __launch_bounds__(256) void k_gemm(const ushort* __restrict__ A,
                                              const ushort* __restrict__ Bt,
                                              void* __restrict__ Cv,
                                              int K, int N) {
  __shared__ __align__(16) ushort lsA[2][4096];
  __shared__ __align__(16) ushort lsB[2][4096];
  const int tid = threadIdx.x;
  const int bm = blockIdx.x, bn = blockIdx.y;
  const int w = tid >> 6, l = tid & 63;
  const int wm = (w >> 1) * 64, wn = (w & 1) * 64;
  const int lr = l & 15, lg = l >> 4;
  f32x4 acc[4][4] = {};
  const int srow = tid >> 2;        // 0..63
  const int scol = (tid & 3) * 8;   // 0,8,16,24
  const ushort* Ag = A + (size_t)(bm * 128 + srow) * K + scol;
  const ushort* Bg = Bt + (size_t)(bn * 128 + srow) * K + scol;
  const int nt = K >> 5;

#define GEMM_ISSUE(BUF, KT)                                       \
  {                                                               \
    GLDS(Ag + (KT), &lsA[BUF][w * 512], 16);                      \
    GLDS(Ag + (size_t)64 * K + (KT), &lsA[BUF][2048 + w * 512], 16); \
    GLDS(Bg + (KT), &lsB[BUF][w * 512], 16);                      \
    GLDS(Bg + (size_t)64 * K + (KT), &lsB[BUF][2048 + w * 512], 16); \
  }

  GEMM_ISSUE(0, 0);
  for (int t = 0; t < nt; ++t) {
    const int cur = t & 1;
    if (t + 1 < nt) {
      GEMM_ISSUE(cur ^ 1, (t + 1) * 32);
      asm volatile("s_waitcnt vmcnt(4)" ::: "memory");  // cur tile landed (own)
    } else {
      asm volatile("s_waitcnt vmcnt(0)" ::: "memory");
    }
    asm volatile("s_barrier" ::: "memory");  // all waves' cur-tile DMA landed
    short8 af[4], bfr[4];
#pragma unroll
    for (int i = 0; i < 4; ++i)
      af[i] = *(const short8*)&lsA[cur][(wm + i * 16 + lr) * 32 + lg * 8];
#pragma unroll
    for (int j = 0; j < 4; ++j)
      bfr[j] = *(const short8*)&lsB[cur][(wn + j * 16 + lr) * 32 + lg * 8];
#pragma unroll
    for (int i = 0; i < 4; ++i)
#pragma unroll
      for (int j = 0; j < 4; ++j)
        acc[i][j] = __builtin_amdgcn_mfma_f32_16x16x32_bf16(af[i], bfr[j], acc[i][j], 0, 0, 0);
    asm volatile("s_barrier" ::: "memory");  // reads done before overwrite
  }
#undef GEMM_ISSUE
  const size_t cbase = (size_t)(bm * 128 + wm + lg * 4) * N + bn * 128 + wn + lr;
  if (BF16OUT) {
    ushort* Cb = (ushort*)Cv + cbase;
#pragma unroll
    for (int i = 0; i < 4; ++i)
#pragma unroll
      for (int j = 0; j < 4; ++j)
#pragma unroll
        for (int r = 0; r < 4; ++r)
          Cb[(size_t)(i * 16 + r) * N + j * 16] = f2bf(acc[i][j][r]);
  } else {
    float* Cb = (float*)Cv + cbase;
#pragma unroll
    for (int i = 0; i < 4; ++i)
#pragma unroll
      for (int j = 0; j < 4; ++j)
#pragma unroll
        for (int r = 0; r < 4; ++r)
          Cb[(size_t)(i * 16 + r) * N + j * 16] = acc[i][j][r];
  }
}

// ------------- SRU recurrence: global_load_lds ring pipeline -------------
template <int KK>
__device__ __forceinline__ void issue_tile(const float* Ub, const ushort* Xb,
                                           float* ldsu, ushort* ldsx, int i,
                                           int t0, int tstep, int lane, int c0,
                                           int rs) {
  const int base = i * 16;
#pragma unroll
  for (int t = 0; t < 16; ++t) {
    int tt = t0 + tstep * (base + t);
    GLDS(Ub + (size_t)tt * rs, ldsu + t * 256, 16);
  }
  if (KK == 3) {
#pragma unroll
    for (int tp = 0; tp < 8; ++tp) {
      int tt = t0 + tstep * (base + tp * 2 + (lane >> 5));
      GLDS(Xb + (size_t)tt * 1024 + c0 + ((lane & 31) << 1), ldsx + tp * 128, 4);
    }
  }
}

template <int KK>
__device__ __forceinline__ void tile_wait(int i) {
  if (KK == 3) {  // 24 loads/tile; newer loads: steady 72 (cap 63), 48, 24, 0
    if (i <= 28)
      asm volatile("s_waitcnt vmcnt(63)" ::: "memory");
    else if (i == 29)
      asm volatile("s_waitcnt vmcnt(48)" ::: "memory");
    else if (i == 30)
      asm volatile("s_waitcnt vmcnt(24)" ::: "memory");
    else
      asm volatile("s_waitcnt vmcnt(0)" ::: "memory");
  } else {        // 16 loads/tile; newer loads: steady 48, 32, 16, 0
    if (i <= 28)
      asm volatile("s_waitcnt vmcnt(48)" ::: "memory");
    else if (i == 29)
      asm volatile("s_waitcnt vmcnt(32)" ::: "memory");
    else if (i == 30)
      asm volatile("s_waitcnt vmcnt(16)" ::: "memory");
    else
      asm volatile("s_waitcnt vmcnt(0)" ::: "memory");
  }
}

// Register-prefetch the whole tile (32 pipelined ds_reads), THEN run the
// serial c-chain on registers. All indices compile-time (full unroll) so
// arrays live in VGPRs, not scratch.
template <int KK>
__device__ __forceinline__ void compute_tile(const float* tu, const ushort* tx,
                                             int i, int t0, int tstep, int lane,
                                             float vf, float vr, float bfv,
                                             float brv, float& c, ushort* Hb) {
  float4 pv[16];
  float xv[16];
#pragma unroll
  for (int s = 0; s < 16; ++s)
    pv[s] = *(const float4*)(tu + s * 256 + lane * 4);
  if (KK == 3) {
#pragma unroll
    for (int s = 0; s < 16; ++s) xv[s] = bf2f(tx[s * 64 + lane]);
  }
#pragma unroll
  for (int s = 0; s < 16; ++s) {
    float u0 = pv[s].x, u1 = pv[s].y, u2 = pv[s].z;
    float u3 = (KK == 4) ? pv[s].w : xv[s];
    float f = 1.f / (1.f + __expf(-(u1 + vf * c + bfv)));
    c = f * c + (1.f - f) * u0;
    float r = 1.f / (1.f + __expf(-(u2 + vr * c + brv)));
    float hh = r * c + (1.f - r) * u3;
    Hb[(size_t)(t0 + tstep * (i * 16 + s)) * 1024] = f2bf(hh);
  }
}

template <int KK>
__global__ __launch_bounds__(64) void sru_rec2(const float* __restrict__ U,
                                               const ushort* __restrict__ Xres,
                                               const float* __restrict__ v,
                                               const float* __restrict__ bb,
                                               ushort* __restrict__ H) {
  const int NT = 32;
  __shared__ __align__(16) float lsU[4][16 * 256];   // 64 KB
  __shared__ __align__(16) ushort lsX[4][16 * 64];   // 8 KB (KK3 only)
  const int lane = threadIdx.x;
  const int blk = blockIdx.x;                            // 0..255
  const int b = blk >> 4, rem = blk & 15, dir = rem >> 3, c0 = (rem & 7) << 6;
  const int h = c0 + lane;
  const float vf = v[dir * 512 + h], vr = v[1024 + dir * 512 + h];
  const float bfv = bb[dir * 512 + h], brv = bb[1024 + dir * 512 + h];
  const int rs = 1024 * KK;
  const int tstep = dir ? -1 : 1;
  const int t0 = dir ? 511 : 0;
  const float* Ub = U + (size_t)b * 512 * rs + dir * 512 * KK + (size_t)h * KK;
  const ushort* Xb = Xres + (size_t)b * 512 * 1024 + dir * 512;
  ushort* Hb = H + (size_t)b * 512 * 1024 + dir * 512 + h;

  issue_tile<KK>(Ub, Xb, &lsU[0][0], &lsX[0][0], 0, t0, tstep, lane, c0, rs);
  issue_tile<KK>(Ub, Xb, &lsU[1][0], &lsX[1][0], 1, t0, tstep, lane, c0, rs);
  issue_tile<KK>(Ub, Xb, &lsU[2][0], &lsX[2][0], 2, t0, tstep, lane, c0, rs);

  float c = 0.f;
#pragma unroll 1
  for (int ii = 0; ii < NT / 4; ++ii) {
#define TILE_J(J)                                                              \
    {                                                                          \
      const int i = ii * 4 + (J);                                              \
      if (i + 3 < NT)                                                          \
        issue_tile<KK>(Ub, Xb, &lsU[((J) + 3) & 3][0], &lsX[((J) + 3) & 3][0], \
                       i + 3, t0, tstep, lane, c0, rs);                        \
      tile_wait<KK>(i);                                                        \
      compute_tile<KK>(&lsU[(J) & 3][0], &lsX[(J) & 3][0], i, t0, tstep, lane, \
                       vf, vr, bfv, brv, c, Hb);                               \
    }
    TILE_J(0) TILE_J(1) TILE_J(2) TILE_J(3)
#undef TILE_J
  }
}

// ------------- head helpers -------------
__global__ __launch_bounds__(256) void k_buildW2(const float* __restrict__ w2l,
                                                 const float* __restrict__ w2m,
                                                 const float* __restrict__ w2k,
                                                 ushort* __restrict__ Wt2) {
  int i = blockIdx.x * 256 + threadIdx.x;  // over 128*1024
  if (i >= 128 * 1024) return;
  int n = i >> 10, k = i & 1023;
  float vv = 0.f;
  if (n < 21 && k < 512) vv = w2l[k * 21 + n];
  else if (n >= 21 && n < 23 && k >= 512) vv = w2m[(k - 512) * 2 + (n - 21)];
  else if (n >= 23 && n < 25 && k >= 512) vv = w2k[(k - 512) * 2 + (n - 23)];
  Wt2[i] = f2bf(vv);
}

__global__ __launch_bounds__(64) void k_bias25(const float* __restrict__ b1l,
                                               const float* __restrict__ b1a,
                                               const float* __restrict__ w2l,
                                               const float* __restrict__ b2l,
                                               const float* __restrict__ w2m,
                                               const float* __restrict__ b2m,
                                               const float* __restrict__ w2k,
                                               const float* __restrict__ b2k,
                                               float* __restrict__ b2adj) {
  int o = threadIdx.x;
  if (o >= 25) return;
  float s;
  if (o < 21) {
    s = b2l[o];
    for (int k = 0; k < 512; ++k) s += b1l[k] * w2l[k * 21 + o];
  } else if (o < 23) {
    s = b2m[o - 21];
    for (int k = 0; k < 512; ++k) s += b1a[k] * w2m[k * 2 + (o - 21)];
  } else {
    s = b2k[o - 23];
    for (int k = 0; k < 512; ++k) s += b1a[k] * w2k[k * 2 + (o - 23)];
  }
  b2adj[o] = s;
}

__global__ __launch_bounds__(64) void k_act(const float* __restrict__ T,
                                            const float* __restrict__ b2adj,
                                            float* __restrict__ out) {
  const int row = blockIdx.x;
  const int lane = threadIdx.x;
  float myv = 0.f;
  if (lane < 25) myv = T[(size_t)row * 128 + lane] + b2adj[lane];
  float x = (lane < 21) ? myv : -1e30f;
#pragma unroll
  for (int off = 32; off; off >>= 1) x = fmaxf(x, __shfl_xor(x, off));
  float e = (lane < 21) ? expf(myv - x) : 0.f;
#pragma unroll
  for (int off = 32; off; off >>= 1) e += __shfl_xor(e, off);
  float lse = x + logf(e);
  if (lane < 21) {
    out[(size_t)row * 21 + lane] = myv - lse;
  } else if (lane < 23) {
    out[172032 + row * 2 + (lane - 21)] = tanhf(myv) * 3.14159265358979323846f;
  } else if (lane < 25) {
    float sp = (myv > 20.f) ? myv : log1pf(expf(myv));
    out[188416 + row * 2 + (lane - 23)] = 5.f + sp;
  }
}

extern "C" void kernel_launch(void* const* d_in, const int* in_sizes, int n_in,
                              void* d_out, int out_size, void* d_ws, size_t ws_size,
                              hipStream_t stream) {
  (void)in_sizes; (void)n_in; (void)out_size; (void)ws_size;
  const float* input = (const float*)d_in[0];
  const float* sw[6]; const float* sv[6]; const float* sb[6];
  for (int l = 0; l < 6; ++l) {
    sw[l] = (const float*)d_in[2 + 3 * l];
    sv[l] = (const float*)d_in[3 + 3 * l];
    sb[l] = (const float*)d_in[4 + 3 * l];
  }
  const float* fc1lw = (const float*)d_in[20];
  const float* fc1lb = (const float*)d_in[21];
  const float* fc2lw = (const float*)d_in[22];
  const float* fc2lb = (const float*)d_in[23];
  const float* fc1aw = (const float*)d_in[24];
  const float* fc1ab = (const float*)d_in[25];
  const float* fc2mw = (const float*)d_in[26];
  const float* fc2mb = (const float*)d_in[27];
  const float* fc2kw = (const float*)d_in[28];
  const float* fc2kb = (const float*)d_in[29];

  char* ws = (char*)d_ws;
  float* U = (float*)ws;                                   // 128 MiB
  ushort* Hcat2 = (ushort*)ws;                             // 16 MiB (reuses U after layers)
  float* T = (float*)(ws + 67108864);                      // 4 MiB (inside old U region)
  ushort* H0 = (ushort*)(ws + 134217728);                  // 16 MiB
  ushort* H1 = (ushort*)(ws + 150994944);                  // 16 MiB
  ushort* X0 = (ushort*)(ws + 167772160);                  // 8 MiB
  const size_t wbase = 176160768;
  ushort* Wtl[6];
  Wtl[0] = (ushort*)(ws + wbase);                          // 4 MiB
  for (int l = 1; l < 6; ++l)
    Wtl[l] = (ushort*)(ws + wbase + 4194304 + (size_t)(l - 1) * 6291456);  // 6 MiB each
  ushort* Wfc = (ushort*)(ws + wbase + 4194304 + 5ull * 6291456);          // 2 MiB
  ushort* Wt2 = (ushort*)(ws + wbase + 37748736);          // 256 KiB
  float* b2adj = (float*)(ws + wbase + 38010880);          // 100 B

  // 1. input -> bf16; head weight prep
  k_cvt<<<4096, 256, 0, stream>>>(input, X0, 8192 * 512 / 4);
  k_buildW2<<<512, 256, 0, stream>>>(fc2lw, fc2mw, fc2kw, Wt2);
  k_bias25<<<1, 64, 0, stream>>>(fc1lb, fc1ab, fc2lw, fc2lb, fc2mw, fc2mb,
                                 fc2kw, fc2kb, b2adj);

  // 2. weight transposes -> bf16 [N][K]
  k_transpose<<<dim3(4096 / 32, 512 / 32), dim3(32, 8), 0, stream>>>(sw[0], Wtl[0], 4096, 512);
  for (int l = 1; l < 6; ++l)
    k_transpose<<<dim3(3072 / 32, 1024 / 32), dim3(32, 8), 0, stream>>>(sw[l], Wtl[l], 3072, 1024);
  k_transpose<<<dim3(512 / 32, 1024 / 32), dim3(32, 8), 0, stream>>>(fc1lw, Wfc, 512, 1024);
  k_transpose<<<dim3(512 / 32, 1024 / 32), dim3(32, 8), 0, stream>>>(fc1aw, Wfc + (size_t)512 * 1024, 512, 1024);

  // 3. SRU layers
  for (int l = 0; l < 6; ++l) {
    const ushort* Ain = (l == 0) ? X0 : ((l & 1) ? H0 : H1);
    ushort* Hout = (l & 1) ? H1 : H0;
    int K = (l == 0) ? 512 : 1024;
    int N = (l == 0) ? 4096 : 3072;
    k_gemm<0><<<dim3(64, N / 128), 256, 0, stream>>>(Ain, Wtl[l], U, K, N);
    if (l == 0)
      sru_rec2<4><<<256, 64, 0, stream>>>(U, X0 /*unused*/, sv[l], sb[l], Hout);
    else
      sru_rec2<3><<<256, 64, 0, stream>>>(U, Ain, sv[l], sb[l], Hout);
  }

  // 4. head fc1 (logits|angles fused), bf16 out: [8192,1024] = H1 x Wfc
  k_gemm<1><<<dim3(64, 8), 256, 0, stream>>>(H1, Wfc, Hcat2, 1024, 1024);

  // 5. head fc2: [8192,128] = Hcat2[8192,1024] x Wt2[128,1024]
  k_gemm<0><<<dim3(64, 1), 256, 0, stream>>>(Hcat2, Wt2, T, 1024, 128);

  // 6. activations -> out
  k_act<<<8192, 64, 0, stream>>>(T, b2adj, (float*)d_out);
}

// Round 7
// 958.047 us; speedup vs baseline: 1.1703x; 1.0531x over previous
//
#include <hip/hip_runtime.h>

typedef __attribute__((ext_vector_type(8))) short short8;
typedef __attribute__((ext_vector_type(4))) float f32x4;

__device__ __forceinline__ ushort f2bf(float x) {
  unsigned u = __builtin_bit_cast(unsigned, x);
  u = (u + 0x7fffu + ((u >> 16) & 1u)) >> 16;
  return (ushort)u;
}
__device__ __forceinline__ float bf2f(ushort x) {
  return __builtin_bit_cast(float, ((unsigned)x) << 16);
}

// global -> LDS direct DMA (used by k_gemm only; needs many waves/CU to pay)
#define AS1CP(p) ((const __attribute__((address_space(1))) unsigned int*)(p))
#define AS3CP(p) ((__attribute__((address_space(3))) unsigned int*)(p))
#define GLDS(g, l, SZ) __builtin_amdgcn_global_load_lds(AS1CP(g), AS3CP(l), SZ, 0, 0)

// ---------------- input fp32 -> bf16 ----------------
__global__ __launch_bounds__(256) void k_cvt(const float* __restrict__ in,
                                             ushort* __restrict__ out, int n4) {
  int i = blockIdx.x * 256 + threadIdx.x;
  if (i >= n4) return;
  float4 v = reinterpret_cast<const float4*>(in)[i];
  ushort4 o;
  o.x = f2bf(v.x); o.y = f2bf(v.y); o.z = f2bf(v.z); o.w = f2bf(v.w);
  reinterpret_cast<ushort4*>(out)[i] = o;
}

// ------------- transpose fp32 [K][N] -> bf16 [N][K] -------------
__global__ __launch_bounds__(256) void k_transpose(const float* __restrict__ W,
                                                   ushort* __restrict__ Wt,
                                                   int N, int K) {
  __shared__ float tile[32][33];
  int bx = blockIdx.x * 32;  // N dim
  int by = blockIdx.y * 32;  // K dim
  int tx = threadIdx.x, ty = threadIdx.y;  // 32 x 8
#pragma unroll
  for (int i = 0; i < 32; i += 8)
    tile[ty + i][tx] = W[(size_t)(by + ty + i) * N + bx + tx];
  __syncthreads();
#pragma unroll
  for (int i = 0; i < 32; i += 8)
    Wt[(size_t)(bx + ty + i) * K + by + tx] = f2bf(tile[tx][ty + i]);
}

// ------------- GEMM: C[M][N] = A[M][K] bf16 * Bt[N][K] bf16 -------------
// 128x128 tile, BK=32, 256 threads (4 waves 2x2 of 64x64). Double-buffered
// global_load_lds staging, counted vmcnt(4), raw s_barrier pair per K-step.
template <int BF16OUT>
__global__ __launch_bounds__(256) void k_gemm(const ushort* __restrict__ A,
                                              const ushort* __restrict__ Bt,
                                              void* __restrict__ Cv,
                                              int K, int N) {
  __shared__ __align__(16) ushort lsA[2][4096];
  __shared__ __align__(16) ushort lsB[2][4096];
  const int tid = threadIdx.x;
  const int bm = blockIdx.x, bn = blockIdx.y;
  const int w = tid >> 6, l = tid & 63;
  const int wm = (w >> 1) * 64, wn = (w & 1) * 64;
  const int lr = l & 15, lg = l >> 4;
  f32x4 acc[4][4] = {};
  const int srow = tid >> 2;        // 0..63
  const int scol = (tid & 3) * 8;   // 0,8,16,24
  const ushort* Ag = A + (size_t)(bm * 128 + srow) * K + scol;
  const ushort* Bg = Bt + (size_t)(bn * 128 + srow) * K + scol;
  const int nt = K >> 5;

#define GEMM_ISSUE(BUF, KT)                                       \
  {                                                               \
    GLDS(Ag + (KT), &lsA[BUF][w * 512], 16);                      \
    GLDS(Ag + (size_t)64 * K + (KT), &lsA[BUF][2048 + w * 512], 16); \
    GLDS(Bg + (KT), &lsB[BUF][w * 512], 16);                      \
    GLDS(Bg + (size_t)64 * K + (KT), &lsB[BUF][2048 + w * 512], 16); \
  }

  GEMM_ISSUE(0, 0);
  for (int t = 0; t < nt; ++t) {
    const int cur = t & 1;
    if (t + 1 < nt) {
      GEMM_ISSUE(cur ^ 1, (t + 1) * 32);
      asm volatile("s_waitcnt vmcnt(4)" ::: "memory");
    } else {
      asm volatile("s_waitcnt vmcnt(0)" ::: "memory");
    }
    asm volatile("s_barrier" ::: "memory");
    short8 af[4], bfr[4];
#pragma unroll
    for (int i = 0; i < 4; ++i)
      af[i] = *(const short8*)&lsA[cur][(wm + i * 16 + lr) * 32 + lg * 8];
#pragma unroll
    for (int j = 0; j < 4; ++j)
      bfr[j] = *(const short8*)&lsB[cur][(wn + j * 16 + lr) * 32 + lg * 8];
#pragma unroll
    for (int i = 0; i < 4; ++i)
#pragma unroll
      for (int j = 0; j < 4; ++j)
        acc[i][j] = __builtin_amdgcn_mfma_f32_16x16x32_bf16(af[i], bfr[j], acc[i][j], 0, 0, 0);
    asm volatile("s_barrier" ::: "memory");
  }
#undef GEMM_ISSUE
  const size_t cbase = (size_t)(bm * 128 + wm + lg * 4) * N + bn * 128 + wn + lr;
  if (BF16OUT) {
    ushort* Cb = (ushort*)Cv + cbase;
#pragma unroll
    for (int i = 0; i < 4; ++i)
#pragma unroll
      for (int j = 0; j < 4; ++j)
#pragma unroll
        for (int r = 0; r < 4; ++r)
          Cb[(size_t)(i * 16 + r) * N + j * 16] = f2bf(acc[i][j][r]);
  } else {
    float* Cb = (float*)Cv + cbase;
#pragma unroll
    for (int i = 0; i < 4; ++i)
#pragma unroll
      for (int j = 0; j < 4; ++j)
#pragma unroll
        for (int r = 0; r < 4; ++r)
          Cb[(size_t)(i * 16 + r) * N + j * 16] = acc[i][j][r];
  }
}

// ------------- SRU recurrence v4: REGISTER ring pipeline -------------
// One wave per (b, dir, 64-channel chunk). 4 register buffers x 16 steps,
// all statically indexed (macros with literal J). Per tile: counted vmcnt
// wait -> compute from registers -> issue tile i+3's plain global loads.
// Per-wave VMEM queue (63 ops) gives ~2 tiles (~36-48 KB) in flight.
template <int KK>
__device__ __forceinline__ void tile_wait3(int i) {
  if (KK == 3) {  // 32 loads/tile; newer loads at wait: 64, 32, 0
    if (i <= 29)
      asm volatile("s_waitcnt vmcnt(63)" ::: "memory");
    else if (i == 30)
      asm volatile("s_waitcnt vmcnt(32)" ::: "memory");
    else
      asm volatile("s_waitcnt vmcnt(0)" ::: "memory");
  } else {        // 16 loads/tile; newer loads: 32, 16, 0
    if (i <= 29)
      asm volatile("s_waitcnt vmcnt(32)" ::: "memory");
    else if (i == 30)
      asm volatile("s_waitcnt vmcnt(16)" ::: "memory");
    else
      asm volatile("s_waitcnt vmcnt(0)" ::: "memory");
  }
}

template <int KK>
__global__ __launch_bounds__(64, 1) void sru_rec3(const float* __restrict__ U,
                                                  const ushort* __restrict__ Xres,
                                                  const float* __restrict__ v,
                                                  const float* __restrict__ bb,
                                                  ushort* __restrict__ H) {
  const int lane = threadIdx.x;
  const int blk = blockIdx.x;                            // 0..255
  const int b = blk >> 4, rem = blk & 15, dir = rem >> 3, c0 = (rem & 7) << 6;
  const int h = c0 + lane;
  const float vf = v[dir * 512 + h], vr = v[1024 + dir * 512 + h];
  const float bfv = bb[dir * 512 + h], brv = bb[1024 + dir * 512 + h];
  const int rs = 1024 * KK;
  const int tstep = dir ? -1 : 1;
  const int t0 = dir ? 511 : 0;
  const float* Ub = U + (size_t)b * 512 * rs + dir * 512 * KK + (size_t)h * KK;
  const ushort* Xb = Xres + (size_t)b * 512 * 1024 + dir * 512 + h;
  ushort* Hb = H + (size_t)b * 512 * 1024 + dir * 512 + h;

  float4 u4[4][16];   // KK4 payload (256 VGPR)
  float3 u3[4][16];   // KK3 payload (192 VGPR)
  ushort xr[4][16];   // KK3 residual (64 VGPR)

#define SR_ISSUE(J, TI)                                                        \
  {                                                                            \
    const int base_ = (TI) * 16;                                               \
    _Pragma("unroll")                                                          \
    for (int t = 0; t < 16; ++t) {                                             \
      int tt = t0 + tstep * (base_ + t);                                       \
      if (KK == 4) {                                                           \
        u4[J][t] = *(const float4*)(Ub + (size_t)tt * rs);                     \
      } else {                                                                 \
        u3[J][t] = *(const float3*)(Ub + (size_t)tt * rs);                     \
        xr[J][t] = Xb[(size_t)tt * 1024];                                      \
      }                                                                        \
    }                                                                          \
  }

#define SR_COMP(J, TI)                                                         \
  {                                                                            \
    _Pragma("unroll")                                                          \
    for (int s = 0; s < 16; ++s) {                                             \
      float u0, u1, u2, uR;                                                    \
      if (KK == 4) {                                                           \
        u0 = u4[J][s].x; u1 = u4[J][s].y; u2 = u4[J][s].z; uR = u4[J][s].w;    \
      } else {                                                                 \
        u0 = u3[J][s].x; u1 = u3[J][s].y; u2 = u3[J][s].z; uR = bf2f(xr[J][s]);\
      }                                                                        \
      float f = 1.f / (1.f + __expf(-(u1 + vf * c + bfv)));                    \
      c = f * c + (1.f - f) * u0;                                              \
      float r = 1.f / (1.f + __expf(-(u2 + vr * c + brv)));                    \
      float hh = r * c + (1.f - r) * uR;                                       \
      Hb[(size_t)(t0 + tstep * ((TI) * 16 + s)) * 1024] = f2bf(hh);            \
    }                                                                          \
  }

  SR_ISSUE(0, 0)
  SR_ISSUE(1, 1)
  SR_ISSUE(2, 2)

  float c = 0.f;
#pragma unroll 1
  for (int ii = 0; ii < 8; ++ii) {
#define TILE_J(J)                                                              \
    {                                                                          \
      const int i = ii * 4 + (J);                                              \
      tile_wait3<KK>(i);                                                       \
      SR_COMP(J, i)                                                            \
      if (i + 3 < 32) SR_ISSUE((((J) + 3) & 3), i + 3)                         \
    }
    TILE_J(0) TILE_J(1) TILE_J(2) TILE_J(3)
#undef TILE_J
  }
#undef SR_ISSUE
#undef SR_COMP
}

// ------------- head helpers -------------
__global__ __launch_bounds__(256) void k_buildW2(const float* __restrict__ w2l,
                                                 const float* __restrict__ w2m,
                                                 const float* __restrict__ w2k,
                                                 ushort* __restrict__ Wt2) {
  int i = blockIdx.x * 256 + threadIdx.x;  // over 128*1024
  if (i >= 128 * 1024) return;
  int n = i >> 10, k = i & 1023;
  float vv = 0.f;
  if (n < 21 && k < 512) vv = w2l[k * 21 + n];
  else if (n >= 21 && n < 23 && k >= 512) vv = w2m[(k - 512) * 2 + (n - 21)];
  else if (n >= 23 && n < 25 && k >= 512) vv = w2k[(k - 512) * 2 + (n - 23)];
  Wt2[i] = f2bf(vv);
}

__global__ __launch_bounds__(64) void k_bias25(const float* __restrict__ b1l,
                                               const float* __restrict__ b1a,
                                               const float* __restrict__ w2l,
                                               const float* __restrict__ b2l,
                                               const float* __restrict__ w2m,
                                               const float* __restrict__ b2m,
                                               const float* __restrict__ w2k,
                                               const float* __restrict__ b2k,
                                               float* __restrict__ b2adj) {
  int o = threadIdx.x;
  if (o >= 25) return;
  float s;
  if (o < 21) {
    s = b2l[o];
    for (int k = 0; k < 512; ++k) s += b1l[k] * w2l[k * 21 + o];
  } else if (o < 23) {
    s = b2m[o - 21];
    for (int k = 0; k < 512; ++k) s += b1a[k] * w2m[k * 2 + (o - 21)];
  } else {
    s = b2k[o - 23];
    for (int k = 0; k < 512; ++k) s += b1a[k] * w2k[k * 2 + (o - 23)];
  }
  b2adj[o] = s;
}

__global__ __launch_bounds__(64) void k_act(const float* __restrict__ T,
                                            const float* __restrict__ b2adj,
                                            float* __restrict__ out) {
  const int row = blockIdx.x;
  const int lane = threadIdx.x;
  float myv = 0.f;
  if (lane < 25) myv = T[(size_t)row * 128 + lane] + b2adj[lane];
  float x = (lane < 21) ? myv : -1e30f;
#pragma unroll
  for (int off = 32; off; off >>= 1) x = fmaxf(x, __shfl_xor(x, off));
  float e = (lane < 21) ? expf(myv - x) : 0.f;
#pragma unroll
  for (int off = 32; off; off >>= 1) e += __shfl_xor(e, off);
  float lse = x + logf(e);
  if (lane < 21) {
    out[(size_t)row * 21 + lane] = myv - lse;
  } else if (lane < 23) {
    out[172032 + row * 2 + (lane - 21)] = tanhf(myv) * 3.14159265358979323846f;
  } else if (lane < 25) {
    float sp = (myv > 20.f) ? myv : log1pf(expf(myv));
    out[188416 + row * 2 + (lane - 23)] = 5.f + sp;
  }
}

extern "C" void kernel_launch(void* const* d_in, const int* in_sizes, int n_in,
                              void* d_out, int out_size, void* d_ws, size_t ws_size,
                              hipStream_t stream) {
  (void)in_sizes; (void)n_in; (void)out_size; (void)ws_size;
  const float* input = (const float*)d_in[0];
  const float* sw[6]; const float* sv[6]; const float* sb[6];
  for (int l = 0; l < 6; ++l) {
    sw[l] = (const float*)d_in[2 + 3 * l];
    sv[l] = (const float*)d_in[3 + 3 * l];
    sb[l] = (const float*)d_in[4 + 3 * l];
  }
  const float* fc1lw = (const float*)d_in[20];
  const float* fc1lb = (const float*)d_in[21];
  const float* fc2lw = (const float*)d_in[22];
  const float* fc2lb = (const float*)d_in[23];
  const float* fc1aw = (const float*)d_in[24];
  const float* fc1ab = (const float*)d_in[25];
  const float* fc2mw = (const float*)d_in[26];
  const float* fc2mb = (const float*)d_in[27];
  const float* fc2kw = (const float*)d_in[28];
  const float* fc2kb = (const float*)d_in[29];

  char* ws = (char*)d_ws;
  float* U = (float*)ws;                                   // 128 MiB
  ushort* Hcat2 = (ushort*)ws;                             // 16 MiB (reuses U after layers)
  float* T = (float*)(ws + 67108864);                      // 4 MiB (inside old U region)
  ushort* H0 = (ushort*)(ws + 134217728);                  // 16 MiB
  ushort* H1 = (ushort*)(ws + 150994944);                  // 16 MiB
  ushort* X0 = (ushort*)(ws + 167772160);                  // 8 MiB
  const size_t wbase = 176160768;
  ushort* Wtl[6];
  Wtl[0] = (ushort*)(ws + wbase);                          // 4 MiB
  for (int l = 1; l < 6; ++l)
    Wtl[l] = (ushort*)(ws + wbase + 4194304 + (size_t)(l - 1) * 6291456);  // 6 MiB each
  ushort* Wfc = (ushort*)(ws + wbase + 4194304 + 5ull * 6291456);          // 2 MiB
  ushort* Wt2 = (ushort*)(ws + wbase + 37748736);          // 256 KiB
  float* b2adj = (float*)(ws + wbase + 38010880);          // 100 B

  // 1. input -> bf16; head weight prep
  k_cvt<<<4096, 256, 0, stream>>>(input, X0, 8192 * 512 / 4);
  k_buildW2<<<512, 256, 0, stream>>>(fc2lw, fc2mw, fc2kw, Wt2);
  k_bias25<<<1, 64, 0, stream>>>(fc1lb, fc1ab, fc2lw, fc2lb, fc2mw, fc2mb,
                                 fc2kw, fc2kb, b2adj);

  // 2. weight transposes -> bf16 [N][K]
  k_transpose<<<dim3(4096 / 32, 512 / 32), dim3(32, 8), 0, stream>>>(sw[0], Wtl[0], 4096, 512);
  for (int l = 1; l < 6; ++l)
    k_transpose<<<dim3(3072 / 32, 1024 / 32), dim3(32, 8), 0, stream>>>(sw[l], Wtl[l], 3072, 1024);
  k_transpose<<<dim3(512 / 32, 1024 / 32), dim3(32, 8), 0, stream>>>(fc1lw, Wfc, 512, 1024);
  k_transpose<<<dim3(512 / 32, 1024 / 32), dim3(32, 8), 0, stream>>>(fc1aw, Wfc + (size_t)512 * 1024, 512, 1024);

  // 3. SRU layers
  for (int l = 0; l < 6; ++l) {
    const ushort* Ain = (l == 0) ? X0 : ((l & 1) ? H0 : H1);
    ushort* Hout = (l & 1) ? H1 : H0;
    int K = (l == 0) ? 512 : 1024;
    int N = (l == 0) ? 4096 : 3072;
    k_gemm<0><<<dim3(64, N / 128), 256, 0, stream>>>(Ain, Wtl[l], U, K, N);
    if (l == 0)
      sru_rec3<4><<<256, 64, 0, stream>>>(U, X0 /*unused*/, sv[l], sb[l], Hout);
    else
      sru_rec3<3><<<256, 64, 0, stream>>>(U, Ain, sv[l], sb[l], Hout);
  }

  // 4. head fc1 (logits|angles fused), bf16 out: [8192,1024] = H1 x Wfc
  k_gemm<1><<<dim3(64, 8), 256, 0, stream>>>(H1, Wfc, Hcat2, 1024, 1024);

  // 5. head fc2: [8192,128] = Hcat2[8192,1024] x Wt2[128,1024]
  k_gemm<0><<<dim3(64, 1), 256, 0, stream>>>(Hcat2, Wt2, T, 1024, 128);

  // 6. activations -> out
  k_act<<<8192, 64, 0, stream>>>(T, b2adj, (float*)d_out);
}

// Round 8
// 885.327 us; speedup vs baseline: 1.2664x; 1.0821x over previous
//
#include <hip/hip_runtime.h>

typedef __attribute__((ext_vector_type(8))) short short8;
typedef __attribute__((ext_vector_type(4))) float f32x4;

__device__ __forceinline__ ushort f2bf(float x) {
  unsigned u = __builtin_bit_cast(unsigned, x);
  u = (u + 0x7fffu + ((u >> 16) & 1u)) >> 16;
  return (ushort)u;
}
__device__ __forceinline__ float bf2f(ushort x) {
  return __builtin_bit_cast(float, ((unsigned)x) << 16);
}

// global -> LDS direct DMA (used by k_gemm only; needs many waves/CU to pay)
#define AS1CP(p) ((const __attribute__((address_space(1))) unsigned int*)(p))
#define AS3CP(p) ((__attribute__((address_space(3))) unsigned int*)(p))
#define GLDS(g, l, SZ) __builtin_amdgcn_global_load_lds(AS1CP(g), AS3CP(l), SZ, 0, 0)

// ---------------- input fp32 -> bf16 ----------------
__global__ __launch_bounds__(256) void k_cvt(const float* __restrict__ in,
                                             ushort* __restrict__ out, int n4) {
  int i = blockIdx.x * 256 + threadIdx.x;
  if (i >= n4) return;
  float4 v = reinterpret_cast<const float4*>(in)[i];
  ushort4 o;
  o.x = f2bf(v.x); o.y = f2bf(v.y); o.z = f2bf(v.z); o.w = f2bf(v.w);
  reinterpret_cast<ushort4*>(out)[i] = o;
}

// ------------- transpose fp32 [K][N] -> bf16 [N][K] -------------
__global__ __launch_bounds__(256) void k_transpose(const float* __restrict__ W,
                                                   ushort* __restrict__ Wt,
                                                   int N, int K) {
  __shared__ float tile[32][33];
  int bx = blockIdx.x * 32;  // N dim
  int by = blockIdx.y * 32;  // K dim
  int tx = threadIdx.x, ty = threadIdx.y;  // 32 x 8
#pragma unroll
  for (int i = 0; i < 32; i += 8)
    tile[ty + i][tx] = W[(size_t)(by + ty + i) * N + bx + tx];
  __syncthreads();
#pragma unroll
  for (int i = 0; i < 32; i += 8)
    Wt[(size_t)(bx + ty + i) * K + by + tx] = f2bf(tile[tx][ty + i]);
}

// ------------- GEMM: C[M][N] = A[M][K] bf16 * Bt[N][K] bf16 -------------
// 128x128 tile, BK=32, 256 threads (4 waves 2x2 of 64x64). Double-buffered
// global_load_lds staging, counted vmcnt(4), raw s_barrier pair per K-step.
template <int BF16OUT>
__global__ __launch_bounds__(256) void k_gemm(const ushort* __restrict__ A,
                                              const ushort* __restrict__ Bt,
                                              void* __restrict__ Cv,
                                              int K, int N) {
  __shared__ __align__(16) ushort lsA[2][4096];
  __shared__ __align__(16) ushort lsB[2][4096];
  const int tid = threadIdx.x;
  const int bm = blockIdx.x, bn = blockIdx.y;
  const int w = tid >> 6, l = tid & 63;
  const int wm = (w >> 1) * 64, wn = (w & 1) * 64;
  const int lr = l & 15, lg = l >> 4;
  f32x4 acc[4][4] = {};
  const int srow = tid >> 2;        // 0..63
  const int scol = (tid & 3) * 8;   // 0,8,16,24
  const ushort* Ag = A + (size_t)(bm * 128 + srow) * K + scol;
  const ushort* Bg = Bt + (size_t)(bn * 128 + srow) * K + scol;
  const int nt = K >> 5;

#define GEMM_ISSUE(BUF, KT)                                       \
  {                                                               \
    GLDS(Ag + (KT), &lsA[BUF][w * 512], 16);                      \
    GLDS(Ag + (size_t)64 * K + (KT), &lsA[BUF][2048 + w * 512], 16); \
    GLDS(Bg + (KT), &lsB[BUF][w * 512], 16);                      \
    GLDS(Bg + (size_t)64 * K + (KT), &lsB[BUF][2048 + w * 512], 16); \
  }

  GEMM_ISSUE(0, 0);
  for (int t = 0; t < nt; ++t) {
    const int cur = t & 1;
    if (t + 1 < nt) {
      GEMM_ISSUE(cur ^ 1, (t + 1) * 32);
      asm volatile("s_waitcnt vmcnt(4)" ::: "memory");
    } else {
      asm volatile("s_waitcnt vmcnt(0)" ::: "memory");
    }
    asm volatile("s_barrier" ::: "memory");
    short8 af[4], bfr[4];
#pragma unroll
    for (int i = 0; i < 4; ++i)
      af[i] = *(const short8*)&lsA[cur][(wm + i * 16 + lr) * 32 + lg * 8];
#pragma unroll
    for (int j = 0; j < 4; ++j)
      bfr[j] = *(const short8*)&lsB[cur][(wn + j * 16 + lr) * 32 + lg * 8];
#pragma unroll
    for (int i = 0; i < 4; ++i)
#pragma unroll
      for (int j = 0; j < 4; ++j)
        acc[i][j] = __builtin_amdgcn_mfma_f32_16x16x32_bf16(af[i], bfr[j], acc[i][j], 0, 0, 0);
    asm volatile("s_barrier" ::: "memory");
  }
#undef GEMM_ISSUE
  const size_t cbase = (size_t)(bm * 128 + wm + lg * 4) * N + bn * 128 + wn + lr;
  if (BF16OUT) {
    ushort* Cb = (ushort*)Cv + cbase;
#pragma unroll
    for (int i = 0; i < 4; ++i)
#pragma unroll
      for (int j = 0; j < 4; ++j)
#pragma unroll
        for (int r = 0; r < 4; ++r)
          Cb[(size_t)(i * 16 + r) * N + j * 16] = f2bf(acc[i][j][r]);
  } else {
    float* Cb = (float*)Cv + cbase;
#pragma unroll
    for (int i = 0; i < 4; ++i)
#pragma unroll
      for (int j = 0; j < 4; ++j)
#pragma unroll
        for (int r = 0; r < 4; ++r)
          Cb[(size_t)(i * 16 + r) * N + j * 16] = acc[i][j][r];
  }
}

// ------------- SRU recurrence v5: register ring + 4 waves/CU -------------
// 1024 blocks of 1 wave; only lanes 0..15 active (16 channels per wave).
// Trades lane utilization for 4x waves/CU: 4x outstanding-load capacity and
// 4 interleaved serial chains per CU. Register ring of 4 tiles x 16 steps,
// statically indexed; counted vmcnt hints; compiler waits anchor correctness.
template <int KK>
__device__ __forceinline__ void tile_wait3(int i) {
  if (KK == 3) {  // 32 loads/tile
    if (i <= 29)
      asm volatile("s_waitcnt vmcnt(63)" ::: "memory");
    else if (i == 30)
      asm volatile("s_waitcnt vmcnt(32)" ::: "memory");
    else
      asm volatile("s_waitcnt vmcnt(0)" ::: "memory");
  } else {        // 16 loads/tile
    if (i <= 29)
      asm volatile("s_waitcnt vmcnt(32)" ::: "memory");
    else if (i == 30)
      asm volatile("s_waitcnt vmcnt(16)" ::: "memory");
    else
      asm volatile("s_waitcnt vmcnt(0)" ::: "memory");
  }
}

template <int KK>
__global__ __launch_bounds__(64, 1) void sru_rec4(const float* __restrict__ U,
                                                  const ushort* __restrict__ Xres,
                                                  const float* __restrict__ v,
                                                  const float* __restrict__ bb,
                                                  ushort* __restrict__ H) {
  const int lane = threadIdx.x;
  if (lane >= 16) return;  // 16 active lanes; rest of wave masked
  const int blk = blockIdx.x;                        // 0..1023
  const int b = blk >> 6, rem = blk & 63, dir = rem >> 5, c0 = (rem & 31) << 4;
  const int h = c0 + lane;
  const float vf = v[dir * 512 + h], vr = v[1024 + dir * 512 + h];
  const float bfv = bb[dir * 512 + h], brv = bb[1024 + dir * 512 + h];
  const int rs = 1024 * KK;
  const int tstep = dir ? -1 : 1;
  const int t0 = dir ? 511 : 0;
  const float* Ub = U + (size_t)b * 512 * rs + dir * 512 * KK + (size_t)h * KK;
  const ushort* Xb = Xres + (size_t)b * 512 * 1024 + dir * 512 + h;
  ushort* Hb = H + (size_t)b * 512 * 1024 + dir * 512 + h;

  float4 u4[4][16];   // KK4 payload
  float3 u3[4][16];   // KK3 payload
  ushort xr[4][16];   // KK3 residual

#define SR_ISSUE(J, TI)                                                        \
  {                                                                            \
    const int base_ = (TI) * 16;                                               \
    _Pragma("unroll")                                                          \
    for (int t = 0; t < 16; ++t) {                                             \
      int tt = t0 + tstep * (base_ + t);                                       \
      if (KK == 4) {                                                           \
        u4[J][t] = *(const float4*)(Ub + (size_t)tt * rs);                     \
      } else {                                                                 \
        u3[J][t] = *(const float3*)(Ub + (size_t)tt * rs);                     \
        xr[J][t] = Xb[(size_t)tt * 1024];                                      \
      }                                                                        \
    }                                                                          \
  }

#define SR_COMP(J, TI)                                                         \
  {                                                                            \
    _Pragma("unroll")                                                          \
    for (int s = 0; s < 16; ++s) {                                             \
      float u0, u1, u2, uR;                                                    \
      if (KK == 4) {                                                           \
        u0 = u4[J][s].x; u1 = u4[J][s].y; u2 = u4[J][s].z; uR = u4[J][s].w;    \
      } else {                                                                 \
        u0 = u3[J][s].x; u1 = u3[J][s].y; u2 = u3[J][s].z; uR = bf2f(xr[J][s]);\
      }                                                                        \
      float f = __builtin_amdgcn_rcpf(1.f + __expf(-(u1 + vf * c + bfv)));     \
      c = u0 + f * (c - u0);                                                   \
      float r = __builtin_amdgcn_rcpf(1.f + __expf(-(u2 + vr * c + brv)));     \
      float hh = uR + r * (c - uR);                                            \
      Hb[(size_t)(t0 + tstep * ((TI) * 16 + s)) * 1024] = f2bf(hh);            \
    }                                                                          \
  }

  SR_ISSUE(0, 0)
  SR_ISSUE(1, 1)
  SR_ISSUE(2, 2)

  float c = 0.f;
#pragma unroll 1
  for (int ii = 0; ii < 8; ++ii) {
#define TILE_J(J)                                                              \
    {                                                                          \
      const int i = ii * 4 + (J);                                              \
      tile_wait3<KK>(i);                                                       \
      SR_COMP(J, i)                                                            \
      if (i + 3 < 32) SR_ISSUE((((J) + 3) & 3), i + 3)                         \
    }
    TILE_J(0) TILE_J(1) TILE_J(2) TILE_J(3)
#undef TILE_J
  }
#undef SR_ISSUE
#undef SR_COMP
}

// ------------- head helpers -------------
__global__ __launch_bounds__(256) void k_buildW2(const float* __restrict__ w2l,
                                                 const float* __restrict__ w2m,
                                                 const float* __restrict__ w2k,
                                                 ushort* __restrict__ Wt2) {
  int i = blockIdx.x * 256 + threadIdx.x;  // over 128*1024
  if (i >= 128 * 1024) return;
  int n = i >> 10, k = i & 1023;
  float vv = 0.f;
  if (n < 21 && k < 512) vv = w2l[k * 21 + n];
  else if (n >= 21 && n < 23 && k >= 512) vv = w2m[(k - 512) * 2 + (n - 21)];
  else if (n >= 23 && n < 25 && k >= 512) vv = w2k[(k - 512) * 2 + (n - 23)];
  Wt2[i] = f2bf(vv);
}

__global__ __launch_bounds__(64) void k_bias25(const float* __restrict__ b1l,
                                               const float* __restrict__ b1a,
                                               const float* __restrict__ w2l,
                                               const float* __restrict__ b2l,
                                               const float* __restrict__ w2m,
                                               const float* __restrict__ b2m,
                                               const float* __restrict__ w2k,
                                               const float* __restrict__ b2k,
                                               float* __restrict__ b2adj) {
  int o = threadIdx.x;
  if (o >= 25) return;
  float s;
  if (o < 21) {
    s = b2l[o];
    for (int k = 0; k < 512; ++k) s += b1l[k] * w2l[k * 21 + o];
  } else if (o < 23) {
    s = b2m[o - 21];
    for (int k = 0; k < 512; ++k) s += b1a[k] * w2m[k * 2 + (o - 21)];
  } else {
    s = b2k[o - 23];
    for (int k = 0; k < 512; ++k) s += b1a[k] * w2k[k * 2 + (o - 23)];
  }
  b2adj[o] = s;
}

__global__ __launch_bounds__(64) void k_act(const float* __restrict__ T,
                                            const float* __restrict__ b2adj,
                                            float* __restrict__ out) {
  const int row = blockIdx.x;
  const int lane = threadIdx.x;
  float myv = 0.f;
  if (lane < 25) myv = T[(size_t)row * 128 + lane] + b2adj[lane];
  float x = (lane < 21) ? myv : -1e30f;
#pragma unroll
  for (int off = 32; off; off >>= 1) x = fmaxf(x, __shfl_xor(x, off));
  float e = (lane < 21) ? expf(myv - x) : 0.f;
#pragma unroll
  for (int off = 32; off; off >>= 1) e += __shfl_xor(e, off);
  float lse = x + logf(e);
  if (lane < 21) {
    out[(size_t)row * 21 + lane] = myv - lse;
  } else if (lane < 23) {
    out[172032 + row * 2 + (lane - 21)] = tanhf(myv) * 3.14159265358979323846f;
  } else if (lane < 25) {
    float sp = (myv > 20.f) ? myv : log1pf(expf(myv));
    out[188416 + row * 2 + (lane - 23)] = 5.f + sp;
  }
}

extern "C" void kernel_launch(void* const* d_in, const int* in_sizes, int n_in,
                              void* d_out, int out_size, void* d_ws, size_t ws_size,
                              hipStream_t stream) {
  (void)in_sizes; (void)n_in; (void)out_size; (void)ws_size;
  const float* input = (const float*)d_in[0];
  const float* sw[6]; const float* sv[6]; const float* sb[6];
  for (int l = 0; l < 6; ++l) {
    sw[l] = (const float*)d_in[2 + 3 * l];
    sv[l] = (const float*)d_in[3 + 3 * l];
    sb[l] = (const float*)d_in[4 + 3 * l];
  }
  const float* fc1lw = (const float*)d_in[20];
  const float* fc1lb = (const float*)d_in[21];
  const float* fc2lw = (const float*)d_in[22];
  const float* fc2lb = (const float*)d_in[23];
  const float* fc1aw = (const float*)d_in[24];
  const float* fc1ab = (const float*)d_in[25];
  const float* fc2mw = (const float*)d_in[26];
  const float* fc2mb = (const float*)d_in[27];
  const float* fc2kw = (const float*)d_in[28];
  const float* fc2kb = (const float*)d_in[29];

  char* ws = (char*)d_ws;
  float* U = (float*)ws;                                   // 128 MiB
  ushort* Hcat2 = (ushort*)ws;                             // 16 MiB (reuses U after layers)
  float* T = (float*)(ws + 67108864);                      // 4 MiB (inside old U region)
  ushort* H0 = (ushort*)(ws + 134217728);                  // 16 MiB
  ushort* H1 = (ushort*)(ws + 150994944);                  // 16 MiB
  ushort* X0 = (ushort*)(ws + 167772160);                  // 8 MiB
  const size_t wbase = 176160768;
  ushort* Wtl[6];
  Wtl[0] = (ushort*)(ws + wbase);                          // 4 MiB
  for (int l = 1; l < 6; ++l)
    Wtl[l] = (ushort*)(ws + wbase + 4194304 + (size_t)(l - 1) * 6291456);  // 6 MiB each
  ushort* Wfc = (ushort*)(ws + wbase + 4194304 + 5ull * 6291456);          // 2 MiB
  ushort* Wt2 = (ushort*)(ws + wbase + 37748736);          // 256 KiB
  float* b2adj = (float*)(ws + wbase + 38010880);          // 100 B

  // 1. input -> bf16; head weight prep
  k_cvt<<<4096, 256, 0, stream>>>(input, X0, 8192 * 512 / 4);
  k_buildW2<<<512, 256, 0, stream>>>(fc2lw, fc2mw, fc2kw, Wt2);
  k_bias25<<<1, 64, 0, stream>>>(fc1lb, fc1ab, fc2lw, fc2lb, fc2mw, fc2mb,
                                 fc2kw, fc2kb, b2adj);

  // 2. weight transposes -> bf16 [N][K]
  k_transpose<<<dim3(4096 / 32, 512 / 32), dim3(32, 8), 0, stream>>>(sw[0], Wtl[0], 4096, 512);
  for (int l = 1; l < 6; ++l)
    k_transpose<<<dim3(3072 / 32, 1024 / 32), dim3(32, 8), 0, stream>>>(sw[l], Wtl[l], 3072, 1024);
  k_transpose<<<dim3(512 / 32, 1024 / 32), dim3(32, 8), 0, stream>>>(fc1lw, Wfc, 512, 1024);
  k_transpose<<<dim3(512 / 32, 1024 / 32), dim3(32, 8), 0, stream>>>(fc1aw, Wfc + (size_t)512 * 1024, 512, 1024);

  // 3. SRU layers
  for (int l = 0; l < 6; ++l) {
    const ushort* Ain = (l == 0) ? X0 : ((l & 1) ? H0 : H1);
    ushort* Hout = (l & 1) ? H1 : H0;
    int K = (l == 0) ? 512 : 1024;
    int N = (l == 0) ? 4096 : 3072;
    k_gemm<0><<<dim3(64, N / 128), 256, 0, stream>>>(Ain, Wtl[l], U, K, N);
    if (l == 0)
      sru_rec4<4><<<1024, 64, 0, stream>>>(U, X0 /*unused*/, sv[l], sb[l], Hout);
    else
      sru_rec4<3><<<1024, 64, 0, stream>>>(U, Ain, sv[l], sb[l], Hout);
  }

  // 4. head fc1 (logits|angles fused), bf16 out: [8192,1024] = H1 x Wfc
  k_gemm<1><<<dim3(64, 8), 256, 0, stream>>>(H1, Wfc, Hcat2, 1024, 1024);

  // 5. head fc2: [8192,128] = Hcat2[8192,1024] x Wt2[128,1024]
  k_gemm<0><<<dim3(64, 1), 256, 0, stream>>>(Hcat2, Wt2, T, 1024, 128);

  // 6. activations -> out
  k_act<<<8192, 64, 0, stream>>>(T, b2adj, (float*)d_out);
}

// Round 9
// 808.546 us; speedup vs baseline: 1.3867x; 1.0950x over previous
//
#include <hip/hip_runtime.h>

typedef __attribute__((ext_vector_type(8))) short short8;
typedef __attribute__((ext_vector_type(4))) float f32x4;

__device__ __forceinline__ ushort f2bf(float x) {
  unsigned u = __builtin_bit_cast(unsigned, x);
  u = (u + 0x7fffu + ((u >> 16) & 1u)) >> 16;
  return (ushort)u;
}
__device__ __forceinline__ float bf2f(ushort x) {
  return __builtin_bit_cast(float, ((unsigned)x) << 16);
}

// global -> LDS direct DMA (used by k_gemm only; needs many waves/CU to pay)
#define AS1CP(p) ((const __attribute__((address_space(1))) unsigned int*)(p))
#define AS3CP(p) ((__attribute__((address_space(3))) unsigned int*)(p))
#define GLDS(g, l, SZ) __builtin_amdgcn_global_load_lds(AS1CP(g), AS3CP(l), SZ, 0, 0)

// ---------------- input fp32 -> bf16 ----------------
__global__ __launch_bounds__(256) void k_cvt(const float* __restrict__ in,
                                             ushort* __restrict__ out, int n4) {
  int i = blockIdx.x * 256 + threadIdx.x;
  if (i >= n4) return;
  float4 v = reinterpret_cast<const float4*>(in)[i];
  ushort4 o;
  o.x = f2bf(v.x); o.y = f2bf(v.y); o.z = f2bf(v.z); o.w = f2bf(v.w);
  reinterpret_cast<ushort4*>(out)[i] = o;
}

// ------------- transpose fp32 [K][N] -> bf16 [N][K] -------------
__global__ __launch_bounds__(256) void k_transpose(const float* __restrict__ W,
                                                   ushort* __restrict__ Wt,
                                                   int N, int K) {
  __shared__ float tile[32][33];
  int bx = blockIdx.x * 32;  // N dim
  int by = blockIdx.y * 32;  // K dim
  int tx = threadIdx.x, ty = threadIdx.y;  // 32 x 8
#pragma unroll
  for (int i = 0; i < 32; i += 8)
    tile[ty + i][tx] = W[(size_t)(by + ty + i) * N + bx + tx];
  __syncthreads();
#pragma unroll
  for (int i = 0; i < 32; i += 8)
    Wt[(size_t)(bx + ty + i) * K + by + tx] = f2bf(tile[tx][ty + i]);
}

// ------------- GEMM: C[M][N] = A[M][K] bf16 * Bt[N][K] bf16 -------------
// 128x128 tile, BK=32, 256 threads (4 waves 2x2 of 64x64). Double-buffered
// global_load_lds staging, counted vmcnt(4), raw s_barrier pair per K-step.
// LDS bank-conflict fix: pre-swizzled global source chunk (chunk ^= (row>>1)&3,
// linear LDS dest) + matching XOR on ds_read column -> 8 distinct bank groups
// per 8-lane phase (conflict-free b128).
template <int BF16OUT>
__global__ __launch_bounds__(256) void k_gemm(const ushort* __restrict__ A,
                                              const ushort* __restrict__ Bt,
                                              void* __restrict__ Cv,
                                              int K, int N) {
  __shared__ __align__(16) ushort lsA[2][4096];
  __shared__ __align__(16) ushort lsB[2][4096];
  const int tid = threadIdx.x;
  const int bm = blockIdx.x, bn = blockIdx.y;
  const int w = tid >> 6, l = tid & 63;
  const int wm = (w >> 1) * 64, wn = (w & 1) * 64;
  const int lr = l & 15, lg = l >> 4;
  f32x4 acc[4][4] = {};
  const int srow = tid >> 2;                               // 0..63
  const int scol = (((tid & 3) ^ ((srow >> 1) & 3))) * 8;  // swizzled source chunk
  const ushort* Ag = A + (size_t)(bm * 128 + srow) * K + scol;
  const ushort* Bg = Bt + (size_t)(bn * 128 + srow) * K + scol;
  const int nt = K >> 5;
  const int rxor = (lr >> 1) & 3;                          // read-side XOR

#define GEMM_ISSUE(BUF, KT)                                       \
  {                                                               \
    GLDS(Ag + (KT), &lsA[BUF][w * 512], 16);                      \
    GLDS(Ag + (size_t)64 * K + (KT), &lsA[BUF][2048 + w * 512], 16); \
    GLDS(Bg + (KT), &lsB[BUF][w * 512], 16);                      \
    GLDS(Bg + (size_t)64 * K + (KT), &lsB[BUF][2048 + w * 512], 16); \
  }

  GEMM_ISSUE(0, 0);
  for (int t = 0; t < nt; ++t) {
    const int cur = t & 1;
    if (t + 1 < nt) {
      GEMM_ISSUE(cur ^ 1, (t + 1) * 32);
      asm volatile("s_waitcnt vmcnt(4)" ::: "memory");
    } else {
      asm volatile("s_waitcnt vmcnt(0)" ::: "memory");
    }
    asm volatile("s_barrier" ::: "memory");
    short8 af[4], bfr[4];
#pragma unroll
    for (int i = 0; i < 4; ++i)
      af[i] = *(const short8*)&lsA[cur][(wm + i * 16 + lr) * 32 + ((lg ^ rxor) * 8)];
#pragma unroll
    for (int j = 0; j < 4; ++j)
      bfr[j] = *(const short8*)&lsB[cur][(wn + j * 16 + lr) * 32 + ((lg ^ rxor) * 8)];
#pragma unroll
    for (int i = 0; i < 4; ++i)
#pragma unroll
      for (int j = 0; j < 4; ++j)
        acc[i][j] = __builtin_amdgcn_mfma_f32_16x16x32_bf16(af[i], bfr[j], acc[i][j], 0, 0, 0);
    asm volatile("s_barrier" ::: "memory");
  }
#undef GEMM_ISSUE
  const size_t cbase = (size_t)(bm * 128 + wm + lg * 4) * N + bn * 128 + wn + lr;
  if (BF16OUT) {
    ushort* Cb = (ushort*)Cv + cbase;
#pragma unroll
    for (int i = 0; i < 4; ++i)
#pragma unroll
      for (int j = 0; j < 4; ++j)
#pragma unroll
        for (int r = 0; r < 4; ++r)
          Cb[(size_t)(i * 16 + r) * N + j * 16] = f2bf(acc[i][j][r]);
  } else {
    float* Cb = (float*)Cv + cbase;
#pragma unroll
    for (int i = 0; i < 4; ++i)
#pragma unroll
      for (int j = 0; j < 4; ++j)
#pragma unroll
        for (int r = 0; r < 4; ++r)
          Cb[(size_t)(i * 16 + r) * N + j * 16] = acc[i][j][r];
  }
}

// ------------- SRU recurrence v6: spill-free register ring -------------
// 1024 blocks, 16 active lanes (4 waves/CU). Ring: 4 slots x TS=8 steps,
// statically indexed, sized to FIT VGPRs (KK3: ~160, KK4: ~170 - no scratch).
// Body order: [wait][issue tile i+3][compute tile i]. Constant vmcnt hints,
// safe by construction (<= newer-op count at every wait point).
template <int KK>
__global__ __launch_bounds__(64, 1) void sru_rec5(const float* __restrict__ U,
                                                  const ushort* __restrict__ Xres,
                                                  const float* __restrict__ v,
                                                  const float* __restrict__ bb,
                                                  ushort* __restrict__ H) {
  const int lane = threadIdx.x;
  if (lane >= 16) return;  // 16 active lanes
  const int blk = blockIdx.x;                        // 0..1023
  const int b = blk >> 6, rem = blk & 63, dir = rem >> 5, c0 = (rem & 31) << 4;
  const int h = c0 + lane;
  const float vf = v[dir * 512 + h], vr = v[1024 + dir * 512 + h];
  const float bfv = bb[dir * 512 + h], brv = bb[1024 + dir * 512 + h];
  const float vfn = -vf, vrn = -vr;      // negated (fold sigmoid negation)
  const float kf0 = -bfv, kr0 = -brv;
  const int rs = 1024 * KK;
  const int tstep = dir ? -1 : 1;
  const int t0 = dir ? 511 : 0;
  const float* Ub = U + (size_t)b * 512 * rs + dir * 512 * KK + (size_t)h * KK;
  const ushort* Xb = Xres + (size_t)b * 512 * 1024 + dir * 512 + h;
  ushort* Hb = H + (size_t)b * 512 * 1024 + dir * 512 + h;

  float4 r4[4][8];   // KK4 payload (128 VGPR)
  float3 r3[4][8];   // KK3 payload (96 VGPR)
  ushort xr[4][8];   // KK3 residual (32 VGPR)

#define SR_ISSUE(J, TI)                                                        \
  {                                                                            \
    const int base_ = (TI) * 8;                                                \
    _Pragma("unroll")                                                          \
    for (int t = 0; t < 8; ++t) {                                              \
      int tt = t0 + tstep * (base_ + t);                                       \
      if (KK == 4) {                                                           \
        r4[J][t] = *(const float4*)(Ub + (size_t)tt * rs);                     \
      } else {                                                                 \
        r3[J][t] = *(const float3*)(Ub + (size_t)tt * rs);                     \
        xr[J][t] = Xb[(size_t)tt * 1024];                                      \
      }                                                                        \
    }                                                                          \
  }

#define SR_COMP(J, TI)                                                         \
  {                                                                            \
    _Pragma("unroll")                                                          \
    for (int s = 0; s < 8; ++s) {                                              \
      float u0, u1, u2, uR;                                                    \
      if (KK == 4) {                                                           \
        u0 = r4[J][s].x; u1 = r4[J][s].y; u2 = r4[J][s].z; uR = r4[J][s].w;    \
      } else {                                                                 \
        u0 = r3[J][s].x; u1 = r3[J][s].y; u2 = r3[J][s].z; uR = bf2f(xr[J][s]);\
      }                                                                        \
      float ef = __expf(__builtin_fmaf(vfn, c, kf0 - u1));                     \
      float f = __builtin_amdgcn_rcpf(1.f + ef);                               \
      c = __builtin_fmaf(f, c - u0, u0);                                       \
      float er = __expf(__builtin_fmaf(vrn, c, kr0 - u2));                     \
      float r = __builtin_amdgcn_rcpf(1.f + er);                               \
      float hh = __builtin_fmaf(r, c - uR, uR);                                \
      Hb[(size_t)(t0 + tstep * ((TI) * 8 + s)) * 1024] = f2bf(hh);             \
    }                                                                          \
  }

#define SR_WAIT                                                                \
  {                                                                            \
    if (KK == 3) asm volatile("s_waitcnt vmcnt(32)" ::: "memory");             \
    else         asm volatile("s_waitcnt vmcnt(16)" ::: "memory");             \
  }

  SR_ISSUE(0, 0)
  SR_ISSUE(1, 1)
  SR_ISSUE(2, 2)

  float c = 0.f;
#pragma unroll 1
  for (int ii = 0; ii < 15; ++ii) {
#define TILE_J(J)                                                              \
    {                                                                          \
      const int i = ii * 4 + (J);                                              \
      SR_WAIT                                                                  \
      SR_ISSUE((((J) + 3) & 3), i + 3)                                         \
      SR_COMP(J, i)                                                            \
    }
    TILE_J(0) TILE_J(1) TILE_J(2) TILE_J(3)
#undef TILE_J
  }
  // tail: tiles 60..63 (issue only for i=60 -> tile 63)
  SR_WAIT SR_ISSUE(3, 63) SR_COMP(0, 60)
  SR_WAIT SR_COMP(1, 61)
  SR_WAIT SR_COMP(2, 62)
  asm volatile("s_waitcnt vmcnt(0)" ::: "memory");
  SR_COMP(3, 63)
#undef SR_ISSUE
#undef SR_COMP
#undef SR_WAIT
}

// ------------- head helpers -------------
__global__ __launch_bounds__(256) void k_buildW2(const float* __restrict__ w2l,
                                                 const float* __restrict__ w2m,
                                                 const float* __restrict__ w2k,
                                                 ushort* __restrict__ Wt2) {
  int i = blockIdx.x * 256 + threadIdx.x;  // over 128*1024
  if (i >= 128 * 1024) return;
  int n = i >> 10, k = i & 1023;
  float vv = 0.f;
  if (n < 21 && k < 512) vv = w2l[k * 21 + n];
  else if (n >= 21 && n < 23 && k >= 512) vv = w2m[(k - 512) * 2 + (n - 21)];
  else if (n >= 23 && n < 25 && k >= 512) vv = w2k[(k - 512) * 2 + (n - 23)];
  Wt2[i] = f2bf(vv);
}

__global__ __launch_bounds__(64) void k_bias25(const float* __restrict__ b1l,
                                               const float* __restrict__ b1a,
                                               const float* __restrict__ w2l,
                                               const float* __restrict__ b2l,
                                               const float* __restrict__ w2m,
                                               const float* __restrict__ b2m,
                                               const float* __restrict__ w2k,
                                               const float* __restrict__ b2k,
                                               float* __restrict__ b2adj) {
  int o = threadIdx.x;
  if (o >= 25) return;
  float s;
  if (o < 21) {
    s = b2l[o];
    for (int k = 0; k < 512; ++k) s += b1l[k] * w2l[k * 21 + o];
  } else if (o < 23) {
    s = b2m[o - 21];
    for (int k = 0; k < 512; ++k) s += b1a[k] * w2m[k * 2 + (o - 21)];
  } else {
    s = b2k[o - 23];
    for (int k = 0; k < 512; ++k) s += b1a[k] * w2k[k * 2 + (o - 23)];
  }
  b2adj[o] = s;
}

__global__ __launch_bounds__(64) void k_act(const float* __restrict__ T,
                                            const float* __restrict__ b2adj,
                                            float* __restrict__ out) {
  const int row = blockIdx.x;
  const int lane = threadIdx.x;
  float myv = 0.f;
  if (lane < 25) myv = T[(size_t)row * 128 + lane] + b2adj[lane];
  float x = (lane < 21) ? myv : -1e30f;
#pragma unroll
  for (int off = 32; off; off >>= 1) x = fmaxf(x, __shfl_xor(x, off));
  float e = (lane < 21) ? expf(myv - x) : 0.f;
#pragma unroll
  for (int off = 32; off; off >>= 1) e += __shfl_xor(e, off);
  float lse = x + logf(e);
  if (lane < 21) {
    out[(size_t)row * 21 + lane] = myv - lse;
  } else if (lane < 23) {
    out[172032 + row * 2 + (lane - 21)] = tanhf(myv) * 3.14159265358979323846f;
  } else if (lane < 25) {
    float sp = (myv > 20.f) ? myv : log1pf(expf(myv));
    out[188416 + row * 2 + (lane - 23)] = 5.f + sp;
  }
}

extern "C" void kernel_launch(void* const* d_in, const int* in_sizes, int n_in,
                              void* d_out, int out_size, void* d_ws, size_t ws_size,
                              hipStream_t stream) {
  (void)in_sizes; (void)n_in; (void)out_size; (void)ws_size;
  const float* input = (const float*)d_in[0];
  const float* sw[6]; const float* sv[6]; const float* sb[6];
  for (int l = 0; l < 6; ++l) {
    sw[l] = (const float*)d_in[2 + 3 * l];
    sv[l] = (const float*)d_in[3 + 3 * l];
    sb[l] = (const float*)d_in[4 + 3 * l];
  }
  const float* fc1lw = (const float*)d_in[20];
  const float* fc1lb = (const float*)d_in[21];
  const float* fc2lw = (const float*)d_in[22];
  const float* fc2lb = (const float*)d_in[23];
  const float* fc1aw = (const float*)d_in[24];
  const float* fc1ab = (const float*)d_in[25];
  const float* fc2mw = (const float*)d_in[26];
  const float* fc2mb = (const float*)d_in[27];
  const float* fc2kw = (const float*)d_in[28];
  const float* fc2kb = (const float*)d_in[29];

  char* ws = (char*)d_ws;
  float* U = (float*)ws;                                   // 128 MiB
  ushort* Hcat2 = (ushort*)ws;                             // 16 MiB (reuses U after layers)
  float* T = (float*)(ws + 67108864);                      // 4 MiB (inside old U region)
  ushort* H0 = (ushort*)(ws + 134217728);                  // 16 MiB
  ushort* H1 = (ushort*)(ws + 150994944);                  // 16 MiB
  ushort* X0 = (ushort*)(ws + 167772160);                  // 8 MiB
  const size_t wbase = 176160768;
  ushort* Wtl[6];
  Wtl[0] = (ushort*)(ws + wbase);                          // 4 MiB
  for (int l = 1; l < 6; ++l)
    Wtl[l] = (ushort*)(ws + wbase + 4194304 + (size_t)(l - 1) * 6291456);  // 6 MiB each
  ushort* Wfc = (ushort*)(ws + wbase + 4194304 + 5ull * 6291456);          // 2 MiB
  ushort* Wt2 = (ushort*)(ws + wbase + 37748736);          // 256 KiB
  float* b2adj = (float*)(ws + wbase + 38010880);          // 100 B

  // 1. input -> bf16; head weight prep
  k_cvt<<<4096, 256, 0, stream>>>(input, X0, 8192 * 512 / 4);
  k_buildW2<<<512, 256, 0, stream>>>(fc2lw, fc2mw, fc2kw, Wt2);
  k_bias25<<<1, 64, 0, stream>>>(fc1lb, fc1ab, fc2lw, fc2lb, fc2mw, fc2mb,
                                 fc2kw, fc2kb, b2adj);

  // 2. weight transposes -> bf16 [N][K]
  k_transpose<<<dim3(4096 / 32, 512 / 32), dim3(32, 8), 0, stream>>>(sw[0], Wtl[0], 4096, 512);
  for (int l = 1; l < 6; ++l)
    k_transpose<<<dim3(3072 / 32, 1024 / 32), dim3(32, 8), 0, stream>>>(sw[l], Wtl[l], 3072, 1024);
  k_transpose<<<dim3(512 / 32, 1024 / 32), dim3(32, 8), 0, stream>>>(fc1lw, Wfc, 512, 1024);
  k_transpose<<<dim3(512 / 32, 1024 / 32), dim3(32, 8), 0, stream>>>(fc1aw, Wfc + (size_t)512 * 1024, 512, 1024);

  // 3. SRU layers
  for (int l = 0; l < 6; ++l) {
    const ushort* Ain = (l == 0) ? X0 : ((l & 1) ? H0 : H1);
    ushort* Hout = (l & 1) ? H1 : H0;
    int K = (l == 0) ? 512 : 1024;
    int N = (l == 0) ? 4096 : 3072;
    k_gemm<0><<<dim3(64, N / 128), 256, 0, stream>>>(Ain, Wtl[l], U, K, N);
    if (l == 0)
      sru_rec5<4><<<1024, 64, 0, stream>>>(U, X0 /*unused*/, sv[l], sb[l], Hout);
    else
      sru_rec5<3><<<1024, 64, 0, stream>>>(U, Ain, sv[l], sb[l], Hout);
  }

  // 4. head fc1 (logits|angles fused), bf16 out: [8192,1024] = H1 x Wfc
  k_gemm<1><<<dim3(64, 8), 256, 0, stream>>>(H1, Wfc, Hcat2, 1024, 1024);

  // 5. head fc2: [8192,128] = Hcat2[8192,1024] x Wt2[128,1024]
  k_gemm<0><<<dim3(64, 1), 256, 0, stream>>>(Hcat2, Wt2, T, 1024, 128);

  // 6. activations -> out
  k_act<<<8192, 64, 0, stream>>>(T, b2adj, (float*)d_out);
}